// Round 8
// baseline (25.287 us; speedup 1.0000x reference)
//
#include <hip/hip_runtime.h>

// MTGP covariance, round 8: K-split staging, 16KB LDS, 7 blocks/CU.
// cov[i,j] = sum_z W[ti,z]W[tj,z]*th[z,0]*exp(-0.5*th[z,1]*||Xi-Xj||^2) + 0.002*I
// M=4096, D=64, Z=4, fp32 in/out. Single fused kernel.
// 2080 upper-tri 64x64 tiles, 4 waves (2x2 grid of 32x32). Per block, two
// K-phases (k in [0,32) then [32,64)): stage fp32 X -> in-register bf16 hi/lo
// split -> swizzled LDS panels (4 x 4KB = 16KB) -> ds_read_b128 frags ->
// 12 mfma_f32_16x16x32_bf16 per phase (hh+hl+lh) accumulating in fp32.
// Row norms accumulate in VGPRs across phases (4-lane shuffle reduce),
// published into dead panel LDS. Fused RBF epilogue; direct + (off-diag)
// transpose stores, exact-once coverage, deterministic.

#define M_PTS 4096
#define DIM 64
#define JITTER_F 0.002f
#define NEG_HALF_LOG2E (-0.72134752044448170f)  // -0.5*log2(e)
#define NBLK 2080                                // 64*65/2

typedef __attribute__((ext_vector_type(8))) short short8v;   // 8 bf16
typedef __attribute__((ext_vector_type(4))) float f32x4;

union FragU { short8v v; uint4 u; };

__device__ __forceinline__ float fast_exp2(float x) {
#if defined(__has_builtin)
#if __has_builtin(__builtin_amdgcn_exp2f)
  return __builtin_amdgcn_exp2f(x);
#else
  return exp2f(x);
#endif
#else
  return exp2f(x);
#endif
}

__device__ __forceinline__ unsigned bfr(float x) {  // fp32 -> bf16 (rne), as u16
  unsigned u = __float_as_uint(x);
  return (u + 0x7FFFu + ((u >> 16) & 1u)) >> 16;
}
__device__ __forceinline__ float bff(unsigned h) {  // bf16 bits -> fp32
  return __uint_as_float(h << 16);
}

// Panel (64 rows x 32 ush): 2 rows per 128B line, XOR-swizzled 16B slots.
// ush offset of (row, slot s in 0..3):
__device__ __forceinline__ int poff(int row, int s) {
  return ((row >> 1) << 6) + ((row & 1) << 5) + ((s ^ ((row >> 1) & 3)) << 3);
}

__global__ __launch_bounds__(256, 7) void mtgp_fused(
    const float* __restrict__ X,      // [4096,64]
    const float* __restrict__ W,      // [4,4]
    const float* __restrict__ theta,  // [4,2]
    float* __restrict__ out) {        // [4096,4096]
  __shared__ __align__(16) unsigned short Ahi[2048], Alo[2048];  // 4KB each
  __shared__ __align__(16) unsigned short Bhi[2048], Blo[2048];  // 16KB total

  // ---- decode item -> (u, v), v >= u, 64 slabs; prefix(u) = u*(129-u)/2 ----
  const int item = blockIdx.x;
  int u = (int)(64.5f - sqrtf(4160.25f - 2.0f * (float)item));
  if (u < 0) u = 0;
  if (u > 63) u = 63;
  while (u > 0 && u * (129 - u) / 2 > item) --u;
  while (u < 63 && (u + 1) * (128 - u) / 2 <= item) ++u;
  const int v = u + (item - u * (129 - u) / 2);
  const int grow0 = u << 6, gj0 = v << 6;

  const int tid = threadIdx.x;
  const int srow = tid >> 2, seg = tid & 3;       // staging: 4 threads/row
  const int wid = tid >> 6, lane = tid & 63;
  const int wr = (wid >> 1) << 5;                 // wave row offset (0/32)
  const int wc = (wid & 1) << 5;                  // wave col offset (0/32)
  const int r16 = lane & 15, kg = lane >> 4, kg4 = kg << 2;

  f32x4 acc[2][2];
#pragma unroll
  for (int p = 0; p < 2; ++p) { acc[p][0] = (f32x4)0.0f; acc[p][1] = (f32x4)0.0f; }

  float sA = 0.0f, sB = 0.0f;                     // row-norm partials
  const int lofs = poff(srow, seg);               // staging LDS slot (phase-inv)

#pragma unroll 1
  for (int k0 = 0; k0 < 2; ++k0) {
    // ---- stage phase k0: 8 fp32 of one A row-seg + one B row-seg ----
    {
      const float* pa = X + (size_t)(grow0 + srow) * DIM + k0 * 32 + seg * 8;
      const float* pb = X + (size_t)(gj0 + srow) * DIM + k0 * 32 + seg * 8;
      const float4 a0 = *(const float4*)pa, a1 = *(const float4*)(pa + 4);
      const float4 b0 = *(const float4*)pb, b1 = *(const float4*)(pb + 4);
      sA = fmaf(a0.x, a0.x, sA); sA = fmaf(a0.y, a0.y, sA);
      sA = fmaf(a0.z, a0.z, sA); sA = fmaf(a0.w, a0.w, sA);
      sA = fmaf(a1.x, a1.x, sA); sA = fmaf(a1.y, a1.y, sA);
      sA = fmaf(a1.z, a1.z, sA); sA = fmaf(a1.w, a1.w, sA);
      sB = fmaf(b0.x, b0.x, sB); sB = fmaf(b0.y, b0.y, sB);
      sB = fmaf(b0.z, b0.z, sB); sB = fmaf(b0.w, b0.w, sB);
      sB = fmaf(b1.x, b1.x, sB); sB = fmaf(b1.y, b1.y, sB);
      sB = fmaf(b1.z, b1.z, sB); sB = fmaf(b1.w, b1.w, sB);
      const unsigned h0 = bfr(a0.x), h1 = bfr(a0.y), h2 = bfr(a0.z), h3 = bfr(a0.w);
      const unsigned h4 = bfr(a1.x), h5 = bfr(a1.y), h6 = bfr(a1.z), h7 = bfr(a1.w);
      const uint4 ahv = make_uint4(h0 | (h1 << 16), h2 | (h3 << 16),
                                   h4 | (h5 << 16), h6 | (h7 << 16));
      const uint4 alv = make_uint4(
          bfr(a0.x - bff(h0)) | (bfr(a0.y - bff(h1)) << 16),
          bfr(a0.z - bff(h2)) | (bfr(a0.w - bff(h3)) << 16),
          bfr(a1.x - bff(h4)) | (bfr(a1.y - bff(h5)) << 16),
          bfr(a1.z - bff(h6)) | (bfr(a1.w - bff(h7)) << 16));
      const unsigned g0 = bfr(b0.x), g1 = bfr(b0.y), g2 = bfr(b0.z), g3 = bfr(b0.w);
      const unsigned g4 = bfr(b1.x), g5 = bfr(b1.y), g6 = bfr(b1.z), g7 = bfr(b1.w);
      const uint4 bhv = make_uint4(g0 | (g1 << 16), g2 | (g3 << 16),
                                   g4 | (g5 << 16), g6 | (g7 << 16));
      const uint4 blv = make_uint4(
          bfr(b0.x - bff(g0)) | (bfr(b0.y - bff(g1)) << 16),
          bfr(b0.z - bff(g2)) | (bfr(b0.w - bff(g3)) << 16),
          bfr(b1.x - bff(g4)) | (bfr(b1.y - bff(g5)) << 16),
          bfr(b1.z - bff(g6)) | (bfr(b1.w - bff(g7)) << 16));
      *(uint4*)&Ahi[lofs] = ahv;
      *(uint4*)&Alo[lofs] = alv;
      *(uint4*)&Bhi[lofs] = bhv;
      *(uint4*)&Blo[lofs] = blv;
    }
    __syncthreads();

    // ---- compute phase k0: frags (slot kg) + 12 MFMA ----
    {
      FragU ah[2], al[2], bh[2], bl[2];
#pragma unroll
      for (int p = 0; p < 2; ++p) {
        const int ra = wr + p * 16 + r16;
        const int rb = wc + p * 16 + r16;
        ah[p].u = *(const uint4*)&Ahi[poff(ra, kg)];
        al[p].u = *(const uint4*)&Alo[poff(ra, kg)];
        bh[p].u = *(const uint4*)&Bhi[poff(rb, kg)];
        bl[p].u = *(const uint4*)&Blo[poff(rb, kg)];
      }
#pragma unroll
      for (int p = 0; p < 2; ++p)
#pragma unroll
        for (int q = 0; q < 2; ++q) {
          acc[p][q] = __builtin_amdgcn_mfma_f32_16x16x32_bf16(ah[p].v, bh[q].v, acc[p][q], 0, 0, 0);
          acc[p][q] = __builtin_amdgcn_mfma_f32_16x16x32_bf16(ah[p].v, bl[q].v, acc[p][q], 0, 0, 0);
          acc[p][q] = __builtin_amdgcn_mfma_f32_16x16x32_bf16(al[p].v, bh[q].v, acc[p][q], 0, 0, 0);
        }
    }
    __syncthreads();
  }

  // ---- norms: reduce 4-lane seg groups, publish into dead panel LDS ----
  sA += __shfl_xor(sA, 1); sA += __shfl_xor(sA, 2);
  sB += __shfl_xor(sB, 1); sB += __shfl_xor(sB, 2);
  if (seg == 0) {
    ((float*)Ahi)[srow] = sA;
    ((float*)Ahi)[64 + srow] = sB;
  }
  __syncthreads();
  const float* nrm = (const float*)Ahi;  // [0..63]=A rows, [64..127]=B rows

  // ---- epilogue ----
  const int ti = u >> 4, tj = v >> 4;    // 16 slabs of 64 rows per task
  float czv[4], ezv[4];
#pragma unroll
  for (int z = 0; z < 4; ++z) {
    czv[z] = W[ti * 4 + z] * W[tj * 4 + z] * theta[2 * z];
    ezv[z] = NEG_HALF_LOG2E * theta[2 * z + 1];
  }
  f32x4 sqr[2];
#pragma unroll
  for (int p = 0; p < 2; ++p) sqr[p] = *(const f32x4*)&nrm[wr + p * 16 + kg4];
  float sqc[2];
#pragma unroll
  for (int q = 0; q < 2; ++q) sqc[q] = nrm[64 + wc + q * 16 + r16];

#pragma unroll
  for (int p = 0; p < 2; ++p)
#pragma unroll
    for (int q = 0; q < 2; ++q)
#pragma unroll
      for (int rr = 0; rr < 4; ++rr) {
        const float d = acc[p][q][rr];
        const float sd = fmaxf(fmaf(-2.0f, d, sqr[p][rr] + sqc[q]), 0.0f);
        float val = czv[0] * fast_exp2(ezv[0] * sd);
        val = fmaf(czv[1], fast_exp2(ezv[1] * sd), val);
        val = fmaf(czv[2], fast_exp2(ezv[2] * sd), val);
        val = fmaf(czv[3], fast_exp2(ezv[3] * sd), val);
        if (u == v && wr + p * 16 + kg4 + rr == wc + q * 16 + r16) val += JITTER_F;
        acc[p][q][rr] = val;
      }

  // ---- direct store: rows grow0+wr.., cols gj0+wc.. ----
#pragma unroll
  for (int p = 0; p < 2; ++p)
#pragma unroll
    for (int rr = 0; rr < 4; ++rr) {
      float* rp = out + (size_t)(grow0 + wr + p * 16 + kg4 + rr) * M_PTS + gj0 + wc + r16;
      rp[0] = acc[p][0][rr];
      rp[16] = acc[p][1][rr];
    }
  // ---- transpose store (off-diagonal only): mirror to strictly-below region ----
  if (u != v) {
#pragma unroll
    for (int q = 0; q < 2; ++q)
#pragma unroll
      for (int p = 0; p < 2; ++p) {
        f32x4* tp = (f32x4*)(out + (size_t)(gj0 + wc + q * 16 + r16) * M_PTS + grow0 + wr + p * 16 + kg4);
        *tp = acc[p][q];
      }
  }
}

extern "C" void kernel_launch(void* const* d_in, const int* in_sizes, int n_in,
                              void* d_out, int out_size, void* d_ws, size_t ws_size,
                              hipStream_t stream) {
  const float* x     = (const float*)d_in[0];   // (4,1024,64)
  const float* W     = (const float*)d_in[1];   // (4,4)
  const float* theta = (const float*)d_in[2];   // (4,2)
  float* out = (float*)d_out;                   // (4096,4096)

  mtgp_fused<<<dim3(NBLK), dim3(256), 0, stream>>>(x, W, theta, out);
}